// Round 11
// baseline (461.893 us; speedup 1.0000x reference)
//
#include <hip/hip_runtime.h>
#include <hip/hip_bf16.h>

#define DEVI __device__ __forceinline__

typedef __attribute__((ext_vector_type(8))) short short8;   // 8 bf16 = 4 VGPRs (MFMA A/B frag)
typedef __attribute__((ext_vector_type(4))) float f32x4;    // MFMA C/D frag

constexpr int D    = 2048;
constexpr int DFF  = 5632;
constexpr int NTOK = 2048;   // total tokens (1024 MoE + 1024 dense)
constexpr int NMOE = 1024;
constexpr float KSCALE = 2.0f;  // 32/16

// Augmented-K layouts:
constexpr int KA = 2112;     // up-GEMM K: [x(2048) | 2*xla1(16) | 2*xla3(16) | 0(32)]
constexpr int KH = 5824;     // down-GEMM K: [h(5632) | q_e slots(128) | q_dense(16) | 0(48)]
// up-GEMM N layout: [0,5632)=W1', [5632,11264)=W3', [11264,11392)=A1, [11392,11520)=A3, pad
constexpr int NW     = 11648;  // = 91*128
constexpr int COL_A1 = 11264;
constexpr int COL_A3 = 11392;

DEVI float bf2f(unsigned short u) { return __uint_as_float(((unsigned)u) << 16); }
DEVI unsigned short f2bf(float f) {                       // round-to-nearest-even
  unsigned u = __float_as_uint(f);
  u += 0x7FFFu + ((u >> 16) & 1u);
  return (unsigned short)(u >> 16);
}
DEVI float silu(float x) { return x / (1.f + __expf(-x)); }

// ---------------------------------------------------------------- prep kernels
// data f32 [2048][2048] -> xb bf16 [2048][KA]; cols 2048..KA zeroed (xla fills dense later)
__global__ __launch_bounds__(256) void cast_x_kernel(const float* __restrict__ data,
                                                     unsigned short* __restrict__ xb) {
  const int row = blockIdx.x, tid = threadIdx.x;
  const float* src = data + (size_t)row * D;
  unsigned short* dst = xb + (size_t)row * KA;
  const int c = tid * 8;
  float4 v0 = *(const float4*)(src + c);
  float4 v1 = *(const float4*)(src + c + 4);
  ushort4 o0, o1;
  o0.x = f2bf(v0.x); o0.y = f2bf(v0.y); o0.z = f2bf(v0.z); o0.w = f2bf(v0.w);
  o1.x = f2bf(v1.x); o1.y = f2bf(v1.y); o1.z = f2bf(v1.z); o1.w = f2bf(v1.w);
  *(ushort4*)(dst + c) = o0;
  *(ushort4*)(dst + c + 4) = o1;
  if (tid < 16) {
    ushort4 z; z.x = 0; z.y = 0; z.z = 0; z.w = 0;
    *(ushort4*)(dst + D + tid * 4) = z;
  }
}

// dense tokens: xla = x @ la^T ; write 2*xla into xb aug cols (wave per token)
__global__ __launch_bounds__(256) void xla_kernel(const float* __restrict__ data,
                                                  const float* __restrict__ la1,
                                                  const float* __restrict__ la3,
                                                  unsigned short* __restrict__ xb) {
  const int t = blockIdx.x * 4 + (threadIdx.x >> 6);   // dense token 0..1023
  const int lane = threadIdx.x & 63;
  const float* xr = data + (size_t)(NMOE + t) * D;
  float acc[32];
  #pragma unroll
  for (int r = 0; r < 32; ++r) acc[r] = 0.f;
  for (int k = lane; k < D; k += 64) {
    float xv = xr[k];
    #pragma unroll
    for (int r = 0; r < 16; ++r) {
      acc[r]      = fmaf(xv, la1[r * D + k], acc[r]);
      acc[16 + r] = fmaf(xv, la3[r * D + k], acc[16 + r]);
    }
  }
  #pragma unroll
  for (int r = 0; r < 32; ++r) {
    float v = acc[r];
    #pragma unroll
    for (int s = 32; s > 0; s >>= 1) v += __shfl_xor(v, s);
    acc[r] = v;
  }
  if (lane == 0) {
    unsigned short* dst = xb + (size_t)(NMOE + t) * KA + D;
    #pragma unroll
    for (int r = 0; r < 32; ++r) dst[r] = f2bf(KSCALE * acc[r]);
  }
}

// W1|W3 rows of Btilde: copy row + lb slot in aug cols
__global__ __launch_bounds__(256) void cast_wlb_kernel(const float* __restrict__ W1,
                                                       const float* __restrict__ W3,
                                                       const float* __restrict__ lb1,
                                                       const float* __restrict__ lb3,
                                                       unsigned short* __restrict__ Wt) {
  const int f = blockIdx.x;            // 0..11263
  const int tid = threadIdx.x;
  const bool isW1 = f < DFF;
  const float* src = isW1 ? (W1 + (size_t)f * D) : (W3 + (size_t)(f - DFF) * D);
  unsigned short* dst = Wt + (size_t)f * KA;
  const int c = tid * 8;
  float4 v0 = *(const float4*)(src + c);
  float4 v1 = *(const float4*)(src + c + 4);
  ushort4 o0, o1;
  o0.x = f2bf(v0.x); o0.y = f2bf(v0.y); o0.z = f2bf(v0.z); o0.w = f2bf(v0.w);
  o1.x = f2bf(v1.x); o1.y = f2bf(v1.y); o1.z = f2bf(v1.z); o1.w = f2bf(v1.w);
  *(ushort4*)(dst + c) = o0;
  *(ushort4*)(dst + c + 4) = o1;
  if (tid < 16) {
    unsigned short o[4];
    #pragma unroll
    for (int j = 0; j < 4; ++j) {
      int rel = tid * 4 + j;           // 0..63
      float v = 0.f;
      if (isW1 && rel < 16)                 v = lb1[(size_t)f * 16 + rel];
      if (!isW1 && rel >= 16 && rel < 32)   v = lb3[(size_t)(f - DFF) * 16 + (rel - 16)];
      o[j] = f2bf(v);
    }
    ushort4 ov; ov.x = o[0]; ov.y = o[1]; ov.z = o[2]; ov.w = o[3];
    *(ushort4*)(dst + D + tid * 4) = ov;
  }
}

// A1|A3 rows of Btilde (rows COL_A1..COL_A1+255): copy + zero aug cols
__global__ __launch_bounds__(256) void cast_a13_kernel(const float* __restrict__ A1,
                                                       const float* __restrict__ A3,
                                                       unsigned short* __restrict__ Wt) {
  const int b = blockIdx.x;            // 0..255
  const int tid = threadIdx.x;
  const float* src = (b < 128) ? (A1 + (size_t)b * D) : (A3 + (size_t)(b - 128) * D);
  unsigned short* dst = Wt + (size_t)(COL_A1 + b) * KA;
  const int c = tid * 8;
  float4 v0 = *(const float4*)(src + c);
  float4 v1 = *(const float4*)(src + c + 4);
  ushort4 o0, o1;
  o0.x = f2bf(v0.x); o0.y = f2bf(v0.y); o0.z = f2bf(v0.z); o0.w = f2bf(v0.w);
  o1.x = f2bf(v1.x); o1.y = f2bf(v1.y); o1.z = f2bf(v1.z); o1.w = f2bf(v1.w);
  *(ushort4*)(dst + c) = o0;
  *(ushort4*)(dst + c + 4) = o1;
  if (tid < 16) {
    ushort4 z; z.x = 0; z.y = 0; z.z = 0; z.w = 0;
    *(ushort4*)(dst + D + tid * 4) = z;
  }
}

// W2hat rows: [W2 row | B2_0..7 slots | lb2 slot | 0]
__global__ __launch_bounds__(256) void cast_w2_kernel(const float* __restrict__ W2,
                                                      const float* __restrict__ B2,
                                                      const float* __restrict__ lb2,
                                                      unsigned short* __restrict__ W2t) {
  const int d = blockIdx.x, tid = threadIdx.x;
  const float* src = W2 + (size_t)d * DFF;
  unsigned short* dst = W2t + (size_t)d * KH;
  for (int c = tid * 4; c < DFF; c += 1024) {
    float4 v = *(const float4*)(src + c);
    ushort4 o;
    o.x = f2bf(v.x); o.y = f2bf(v.y); o.z = f2bf(v.z); o.w = f2bf(v.w);
    *(ushort4*)(dst + c) = o;
  }
  if (tid < 48) {
    unsigned short o[4];
    #pragma unroll
    for (int j = 0; j < 4; ++j) {
      int rel = tid * 4 + j;           // 0..191
      float v = 0.f;
      if (rel < 128)      v = B2[(size_t)(rel >> 4) * D * 16 + (size_t)d * 16 + (rel & 15)];
      else if (rel < 144) v = lb2[(size_t)d * 16 + (rel - 128)];
      o[j] = f2bf(v);
    }
    ushort4 ov; ov.x = o[0]; ov.y = o[1]; ov.z = o[2]; ov.w = o[3];
    *(ushort4*)(dst + DFF + tid * 4) = ov;
  }
}

// B1,B3 flat f32->bf16 (each 8*5632*16 = 704*1024 elems)
__global__ __launch_bounds__(256) void cast_flat2_kernel(const float* __restrict__ B1,
                                                         const float* __restrict__ B3,
                                                         unsigned short* __restrict__ B1b,
                                                         unsigned short* __restrict__ B3b) {
  int b = blockIdx.x;                  // 0..1407
  const float* src; unsigned short* dst;
  if (b < 704) { src = B1; dst = B1b; } else { src = B3; dst = B3b; b -= 704; }
  size_t idx = ((size_t)b * 256 + threadIdx.x) * 4;
  float4 v = *(const float4*)(src + idx);
  ushort4 o;
  o.x = f2bf(v.x); o.y = f2bf(v.y); o.z = f2bf(v.z); o.w = f2bf(v.w);
  *(ushort4*)(dst + idx) = o;
}

// A2 (E,R,DFF) -> A2t (E,DFF,R) bf16 ; la2 (R,DFF) -> la2t (DFF,R) bf16
__global__ __launch_bounds__(256) void transpose_ra_kernel(const float* __restrict__ A2,
                                                           const float* __restrict__ la2,
                                                           unsigned short* __restrict__ A2tb,
                                                           unsigned short* __restrict__ la2tb) {
  int f = blockIdx.x * 256 + threadIdx.x;          // 0..5631 (grid.x=22 exact)
  int e = blockIdx.y;                              // 0..7 = A2 expert, 8 = la2
  const float* src = (e < 8) ? (A2 + (size_t)e * 16 * DFF) : la2;
  unsigned short* dst = (e < 8) ? (A2tb + (size_t)e * DFF * 16) : la2tb;
  unsigned short tmp[16];
  #pragma unroll
  for (int r = 0; r < 16; ++r) tmp[r] = f2bf(src[(size_t)r * DFF + f]);
  #pragma unroll
  for (int r = 0; r < 16; ++r) dst[(size_t)f * 16 + r] = tmp[r];
}

// ---------------------------------------------------------------- gating (exact f32)
__global__ __launch_bounds__(256) void gate_kernel(const float* __restrict__ x,
                                                   const float* __restrict__ gW,
                                                   float* __restrict__ logits_out,
                                                   int* __restrict__ gidx,
                                                   float* __restrict__ gwt) {
  int t = blockIdx.x * 4 + (threadIdx.x >> 6);     // one wave per token, 1024 tokens
  int lane = threadIdx.x & 63;
  const float* xr = x + (size_t)t * D;
  float acc[8];
  #pragma unroll
  for (int e = 0; e < 8; ++e) acc[e] = 0.f;
  for (int k = lane; k < D; k += 64) {
    float xv = xr[k];
    #pragma unroll
    for (int e = 0; e < 8; ++e) acc[e] = fmaf(xv, gW[e * D + k], acc[e]);
  }
  #pragma unroll
  for (int e = 0; e < 8; ++e) {
    float v = acc[e];
    #pragma unroll
    for (int s = 32; s > 0; s >>= 1) v += __shfl_xor(v, s);
    acc[e] = v;
  }
  if (lane == 0) {
    #pragma unroll
    for (int e = 0; e < 8; ++e) logits_out[(size_t)t * 8 + e] = acc[e];
    int i1 = 0;
    #pragma unroll
    for (int e = 1; e < 8; ++e) if (acc[e] > acc[i1]) i1 = e;   // ties -> lowest index (jax)
    int i2 = (i1 == 0) ? 1 : 0;
    #pragma unroll
    for (int e = 0; e < 8; ++e) if (e != i1 && acc[e] > acc[i2]) i2 = e;
    float w1 = 1.f / (1.f + expf(acc[i2] - acc[i1]));           // p1/(p1+p2), stable
    gidx[t * 2] = i1; gidx[t * 2 + 1] = i2;
    gwt[t * 2] = w1;  gwt[t * 2 + 1] = 1.f - w1;
  }
}

// ---------------------------------------------------------------- minimal-barrier bf16 GEMM
// C = A(M,K) * B(N,K)^T.  BK=64, per-wave 64x64 output, double-buffered LDS,
// per K-tile: {stage all 8 loads of tile t+1 -> counted vmcnt(8) -> barrier ->
// [16 ds_read + 32 MFMA, compiler-scheduled, NO pinning] -> barrier}.
// XOR-swizzled LDS (granule^row&7, inverse applied on global source) -> 0 conflicts.
// by-FASTEST traversal: consecutive blocks share the B-panel (L2-resident).
// EPI: 1 -> bf16 store; 3 -> f32 plain store.
typedef const void __attribute__((address_space(1)))* gp1_t;
typedef void __attribute__((address_space(3)))* lp3_t;
DEVI void gload_lds16(const void* g, void* l) {
  __builtin_amdgcn_global_load_lds((gp1_t)g, (lp3_t)l, 16, 0, 0);
}
#define S_BARRIER() asm volatile("s_barrier" ::: "memory")

template <int N> DEVI void vmcnt_() {
  static_assert(N == 0 || N == 8, "enumerate literals");
  if constexpr (N == 0) asm volatile("s_waitcnt vmcnt(0)" ::: "memory");
  if constexpr (N == 8) asm volatile("s_waitcnt vmcnt(8)" ::: "memory");
}

template <int BM, int BN, int WM, int WN, int MINW, int EPI>
__global__ __launch_bounds__(WM * WN * 64, MINW) void gemmM(
    const unsigned short* __restrict__ A,
    const unsigned short* __restrict__ B,
    int K,
    float* __restrict__ Cf,
    unsigned short* __restrict__ Cb,
    int ldc, int nby) {
  constexpr int THREADS = WM * WN * 64;
  constexpr int RW = BM / WM;              // 64
  constexpr int CW = BN / WN;              // 64
  static_assert(RW == 64 && CW == 64, "template assumes 64x64 per-wave tile");
  constexpr int ATILE = BM * 128;          // bytes (BM x 64 bf16)
  constexpr int BTILE = BN * 128;
  constexpr int SLOT = ATILE + BTILE;
  constexpr int APARTS = BM * 8 / THREADS;
  constexpr int BPARTS = BN * 8 / THREADS;
  static_assert(APARTS + BPARTS == 8, "vmcnt gate literal assumes 8 loads/tile");

  __shared__ __align__(16) char smem[2 * SLOT];

  const int tid = threadIdx.x;
  const int wave = tid >> 6, lane = tid & 63;
  const int wm = wave / WN, wn = wave % WN;
  const int r15 = lane & 15, g = lane >> 4;

  // XCD-aware bijective block swizzle (nwg % 8 == 0 for all our launches)
  const int nwg = (int)gridDim.x;
  const int bid = (int)blockIdx.x;
  const int wgid = (bid & 7) * (nwg >> 3) + (bid >> 3);
  // by-fastest: consecutive wgids share bx (B-panel stays L2-resident)
  const int by = wgid % nby, bx = wgid / nby;

  const unsigned short* Ablk = A + (size_t)by * BM * K;
  const unsigned short* Bblk = B + (size_t)bx * BN * K;

  int sgoA[APARTS], sgoB[BPARTS];
  #pragma unroll
  for (int j = 0; j < APARTS; ++j) {
    int tt = j * THREADS + tid;
    int row = tt >> 3;
    sgoA[j] = row * K + (((tt & 7) ^ (row & 7)) << 3);
  }
  #pragma unroll
  for (int j = 0; j < BPARTS; ++j) {
    int tt = j * THREADS + tid;
    int row = tt >> 3;
    sgoB[j] = row * K + (((tt & 7) ^ (row & 7)) << 3);
  }
  auto stage = [&](int p, int k0) {
    char* s = smem + p * SLOT;
    #pragma unroll
    for (int j = 0; j < APARTS; ++j)
      gload_lds16((const char*)Ablk + ((size_t)(sgoA[j] + k0) << 1),
                  s + j * (THREADS * 16) + wave * 1024);
    #pragma unroll
    for (int j = 0; j < BPARTS; ++j)
      gload_lds16((const char*)Bblk + ((size_t)(sgoB[j] + k0) << 1),
                  s + ATILE + j * (THREADS * 16) + wave * 1024);
  };

  const int arow0 = (wm * RW + r15) * 128;
  const int brow0 = (wn * CW + r15) * 128;
  const int s0 = ((g ^ (r15 & 7)) << 4);
  const int s1 = (((4 + g) ^ (r15 & 7)) << 4);

  f32x4 acc[4][4];
  #pragma unroll
  for (int m = 0; m < 4; ++m)
    #pragma unroll
    for (int n = 0; n < 4; ++n)
      #pragma unroll
      for (int j = 0; j < 4; ++j) acc[m][n][j] = 0.f;

  const int NT = K >> 6;

  stage(0, 0);

  for (int t = 0; t < NT; ++t) {
    const int p = t & 1;
    if (t + 1 < NT) {
      stage(p ^ 1, (t + 1) << 6);
      vmcnt_<8>();
    } else {
      vmcnt_<0>();
    }
    S_BARRIER();

    const char* sA = smem + p * SLOT;
    const char* sB = sA + ATILE;

    short8 bq[4][2], av[4][2];
    #pragma unroll
    for (int n = 0; n < 4; ++n) {
      bq[n][0] = *(const short8*)(sB + brow0 + n * 2048 + s0);
      bq[n][1] = *(const short8*)(sB + brow0 + n * 2048 + s1);
    }
    #pragma unroll
    for (int m = 0; m < 4; ++m) {
      av[m][0] = *(const short8*)(sA + arow0 + m * 2048 + s0);
      av[m][1] = *(const short8*)(sA + arow0 + m * 2048 + s1);
    }
    #pragma unroll
    for (int m = 0; m < 4; ++m)
      #pragma unroll
      for (int n = 0; n < 4; ++n)
        #pragma unroll
        for (int kk = 0; kk < 2; ++kk)
          acc[m][n] = __builtin_amdgcn_mfma_f32_16x16x32_bf16(
              av[m][kk], bq[n][kk], acc[m][n], 0, 0, 0);

    S_BARRIER();
  }

  // epilogue: C/D layout col=lane&15, row=(lane>>4)*4+reg  [m89-verified]
  const int row0 = by * BM + wm * RW + (g << 2);
  const int col0 = bx * BN + wn * CW + r15;
  #pragma unroll
  for (int m = 0; m < 4; ++m) {
    #pragma unroll
    for (int n = 0; n < 4; ++n) {
      int col = col0 + n * 16;
      #pragma unroll
      for (int j = 0; j < 4; ++j) {
        int row = row0 + m * 16 + j;
        size_t off = (size_t)row * ldc + col;
        float v = acc[m][n][j];
        if (EPI == 1) Cb[off] = f2bf(v);
        else          Cf[off] = v;
      }
    }
  }
}

// ---------------------------------------------------------------- h / combine / q kernel
DEVI float dot16bf(const float* a, const unsigned short* w) {
  short8 w0 = *(const short8*)w;
  short8 w1 = *(const short8*)(w + 8);
  float s0 = 0.f, s1 = 0.f;
  #pragma unroll
  for (int i = 0; i < 8; ++i) {
    s0 = fmaf(a[i],     bf2f((unsigned short)w0[i]), s0);
    s1 = fmaf(a[8 + i], bf2f((unsigned short)w1[i]), s1);
  }
  return s0 + s1;
}

__global__ __launch_bounds__(256) void h_kernel(
    const unsigned short* __restrict__ GU,      // [NTOK][NW] bf16
    const unsigned short* __restrict__ B1b,     // [8][DFF][16]
    const unsigned short* __restrict__ B3b,
    const unsigned short* __restrict__ A2tb,    // [8][DFF][16]
    const unsigned short* __restrict__ la2tb,   // [DFF][16]
    const int* __restrict__ gidx, const float* __restrict__ gwt,
    unsigned short* __restrict__ Hb) {          // [NTOK][KH]
  const int t = blockIdx.x;
  const int tid = threadIdx.x;
  const unsigned short* gu = GU + (size_t)t * NW;
  unsigned short* hrow = Hb + (size_t)t * KH;
  float qacc[32];
  #pragma unroll
  for (int r = 0; r < 32; ++r) qacc[r] = 0.f;
  int e1 = 0, e2 = 1;
  float w1 = 0.f, w2 = 0.f;

  if (t < NMOE) {
    e1 = gidx[t * 2]; e2 = gidx[t * 2 + 1];
    w1 = gwt[t * 2]; w2 = gwt[t * 2 + 1];
    float xa1a[16], xa1b[16], xa3a[16], xa3b[16];
    #pragma unroll
    for (int r = 0; r < 16; ++r) {
      xa1a[r] = bf2f(gu[COL_A1 + e1 * 16 + r]);
      xa1b[r] = bf2f(gu[COL_A1 + e2 * 16 + r]);
      xa3a[r] = bf2f(gu[COL_A3 + e1 * 16 + r]);
      xa3b[r] = bf2f(gu[COL_A3 + e2 * 16 + r]);
    }
    const unsigned short* B1e1 = B1b + (size_t)e1 * DFF * 16;
    const unsigned short* B1e2 = B1b + (size_t)e2 * DFF * 16;
    const unsigned short* B3e1 = B3b + (size_t)e1 * DFF * 16;
    const unsigned short* B3e2 = B3b + (size_t)e2 * DFF * 16;
    const unsigned short* A2e1 = A2tb + (size_t)e1 * DFF * 16;
    const unsigned short* A2e2 = A2tb + (size_t)e2 * DFF * 16;
    for (int i = 0; i < 22; ++i) {
      int f = tid + i * 256;
      float bg = bf2f(gu[f]), bu = bf2f(gu[DFF + f]);
      float dg1 = dot16bf(xa1a, B1e1 + f * 16);
      float du1 = dot16bf(xa3a, B3e1 + f * 16);
      float dg2 = dot16bf(xa1b, B1e2 + f * 16);
      float du2 = dot16bf(xa3b, B3e2 + f * 16);
      float h1 = silu(bg + KSCALE * dg1) * (bu + KSCALE * du1);
      float h2 = silu(bg + KSCALE * dg2) * (bu + KSCALE * du2);
      hrow[f] = f2bf(w1 * h1 + w2 * h2);
      short8 a0 = *(const short8*)(A2e1 + f * 16);
      short8 a1 = *(const short8*)(A2e1 + f * 16 + 8);
      short8 b0 = *(const short8*)(A2e2 + f * 16);
      short8 b1 = *(const short8*)(A2e2 + f * 16 + 8);
      #pragma unroll
      for (int r = 0; r < 8; ++r) {
        qacc[r]      = fmaf(h1, bf2f((unsigned short)a0[r]), qacc[r]);
        qacc[8 + r]  = fmaf(h1, bf2f((unsigned short)a1[r]), qacc[8 + r]);
        qacc[16 + r] = fmaf(h2, bf2f((unsigned short)b0[r]), qacc[16 + r]);
        qacc[24 + r] = fmaf(h2, bf2f((unsigned short)b1[r]), qacc[24 + r]);
      }
    }
  } else {
    // dense: LoRA folded into GU; only h and q = h @ la2^T remain
    for (int i = 0; i < 22; ++i) {
      int f = tid + i * 256;
      float bg = bf2f(gu[f]), bu = bf2f(gu[DFF + f]);
      float h = silu(bg) * bu;
      hrow[f] = f2bf(h);
      short8 a0 = *(const short8*)(la2tb + f * 16);
      short8 a1 = *(const short8*)(la2tb + f * 16 + 8);
      #pragma unroll
      for (int r = 0; r < 8; ++r) {
        qacc[r]     = fmaf(h, bf2f((unsigned short)a0[r]), qacc[r]);
        qacc[8 + r] = fmaf(h, bf2f((unsigned short)a1[r]), qacc[8 + r]);
      }
    }
  }

  // reduce 32 partials across 256 threads
  #pragma unroll
  for (int r = 0; r < 32; ++r) {
    float v = qacc[r];
    #pragma unroll
    for (int s = 32; s > 0; s >>= 1) v += __shfl_xor(v, s);
    qacc[r] = v;
  }
  __shared__ float red[4][32];
  const int wave = tid >> 6, lane = tid & 63;
  if (lane == 0) {
    #pragma unroll
    for (int r = 0; r < 32; ++r) red[wave][r] = qacc[r];
  }
  __syncthreads();
  // write augmented-K tail: cols DFF..DFF+191 (expert q slots, dense slot, pad)
  if (tid < 192) {
    int e = tid >> 4, r = tid & 15;
    float v = 0.f;
    if (t < NMOE) {
      if (e == e1)      v = KSCALE * w1 * (red[0][r] + red[1][r] + red[2][r] + red[3][r]);
      else if (e == e2) v = KSCALE * w2 * (red[0][16 + r] + red[1][16 + r] + red[2][16 + r] + red[3][16 + r]);
    } else {
      if (e == 8)       v = KSCALE * (red[0][r] + red[1][r] + red[2][r] + red[3][r]);
    }
    hrow[DFF + tid] = f2bf(v);
  }
}

// ---------------------------------------------------------------- host
extern "C" void kernel_launch(void* const* d_in, const int* in_sizes, int n_in,
                              void* d_out, int out_size, void* d_ws, size_t ws_size,
                              hipStream_t stream) {
  (void)in_sizes; (void)n_in; (void)out_size; (void)ws_size;
  const float* data = (const float*)d_in[0];
  const float* W1   = (const float*)d_in[1];
  const float* W3   = (const float*)d_in[2];
  const float* W2   = (const float*)d_in[3];
  const float* gW   = (const float*)d_in[4];
  const float* A1   = (const float*)d_in[5];
  const float* B1   = (const float*)d_in[6];
  const float* A3   = (const float*)d_in[7];
  const float* B3   = (const float*)d_in[8];
  const float* A2   = (const float*)d_in[9];
  const float* B2   = (const float*)d_in[10];
  const float* la1  = (const float*)d_in[11];
  const float* lb1  = (const float*)d_in[12];
  const float* la3  = (const float*)d_in[13];
  const float* lb3  = (const float*)d_in[14];
  const float* la2  = (const float*)d_in[15];
  const float* lb2  = (const float*)d_in[16];

  char* w = (char*)d_ws;
  size_t off = 0;
  auto alloc = [&](size_t bytes) -> char* {
    char* p = w + off;
    off += (bytes + 255) & ~(size_t)255;
    return p;
  };
  unsigned short* xb    = (unsigned short*)alloc((size_t)NTOK * KA * 2);      // 8.65 MB
  unsigned short* W13t  = (unsigned short*)alloc((size_t)NW * KA * 2);        // 49.2 MB
  unsigned short* W2t   = (unsigned short*)alloc((size_t)D * KH * 2);         // 23.9 MB
  unsigned short* B1b   = (unsigned short*)alloc((size_t)8 * DFF * 16 * 2);
  unsigned short* B3b   = (unsigned short*)alloc((size_t)8 * DFF * 16 * 2);
  unsigned short* A2tb  = (unsigned short*)alloc((size_t)8 * DFF * 16 * 2);
  unsigned short* la2tb = (unsigned short*)alloc((size_t)DFF * 16 * 2);
  int*   gidx = (int*)alloc((size_t)NMOE * 2 * 4);
  float* gwt  = (float*)alloc((size_t)NMOE * 2 * 4);
  unsigned short* GU    = (unsigned short*)alloc((size_t)NTOK * NW * 2);      // 47.7 MB

  // Aliased scratch: Hb (23.9 MB) into W13t region (dead after up-GEMM)
  unsigned short* Hb = W13t;

  // ---- prep
  cast_x_kernel<<<NTOK, 256, 0, stream>>>(data, xb);
  cast_wlb_kernel<<<2 * DFF, 256, 0, stream>>>(W1, W3, lb1, lb3, W13t);
  cast_a13_kernel<<<256, 256, 0, stream>>>(A1, A3, W13t);
  hipMemsetAsync(W13t + (size_t)(COL_A3 + 128) * KA, 0,
                 (size_t)(NW - (COL_A3 + 128)) * KA * 2, stream);  // pad rows -> 0
  cast_w2_kernel<<<D, 256, 0, stream>>>(W2, B2, lb2, W2t);
  cast_flat2_kernel<<<1408, 256, 0, stream>>>(B1, B3, B1b, B3b);
  transpose_ra_kernel<<<dim3(DFF / 256, 9), 256, 0, stream>>>(A2, la2, A2tb, la2tb);

  // ---- gating (writes logits f32) + dense xla into xb aug cols
  gate_kernel<<<NMOE / 4, 256, 0, stream>>>(data, gW,
      (float*)d_out + (size_t)NTOK * D, gidx, gwt);
  xla_kernel<<<NMOE / 4, 256, 0, stream>>>(data, la1, la3, xb);

  // ---- up-GEMM: 2048 x 11648 x 2112 (augmented K folds dense LoRA), bf16 -> GU
  gemmM<128, 128, 2, 2, 2, 1><<<(NTOK / 128) * (NW / 128), 256, 0, stream>>>(
      xb, W13t, KA, (float*)nullptr, GU, NW, NTOK / 128);

  // ---- h / per-expert q -> Hb augmented rows [h | q slots]
  h_kernel<<<NTOK, 256, 0, stream>>>(GU, B1b, B3b, A2tb, la2tb, gidx, gwt, Hb);

  // ---- down-GEMM: 2048 x 2048 x 5824 (augmented K folds ALL down-LoRA), f32 -> d_out
  gemmM<128, 128, 2, 2, 2, 3><<<(NTOK / 128) * (D / 128), 256, 0, stream>>>(
      Hb, W2t, KH, (float*)d_out, (unsigned short*)nullptr, D, NTOK / 128);
}

// Round 12
// 339.011 us; speedup vs baseline: 1.3625x; 1.3625x over previous
//
#include <hip/hip_runtime.h>
#include <hip/hip_bf16.h>

#define DEVI __device__ __forceinline__

typedef __attribute__((ext_vector_type(8))) short short8;   // 8 bf16 = 4 VGPRs (MFMA A/B frag)
typedef __attribute__((ext_vector_type(4))) float f32x4;    // MFMA C/D frag

constexpr int D    = 2048;
constexpr int DFF  = 5632;
constexpr int NTOK = 2048;   // total tokens (1024 MoE + 1024 dense)
constexpr int NMOE = 1024;
constexpr float KSCALE = 2.0f;  // 32/16

// Augmented-K layouts:
constexpr int KA = 2112;     // up-GEMM K: [x(2048) | 2*xla1(16) | 2*xla3(16) | 0(32)]
constexpr int KH = 5824;     // down-GEMM K: [h(5632) | q_e slots(128) | q_dense(16) | 0(48)]
// up-GEMM N layout: [0,5632)=W1', [5632,11264)=W3', [11264,11392)=A1, [11392,11520)=A3, pad
constexpr int NW     = 11648;  // = 91*128
constexpr int COL_A1 = 11264;
constexpr int COL_A3 = 11392;

DEVI float bf2f(unsigned short u) { return __uint_as_float(((unsigned)u) << 16); }
DEVI unsigned short f2bf(float f) {                       // round-to-nearest-even
  unsigned u = __float_as_uint(f);
  u += 0x7FFFu + ((u >> 16) & 1u);
  return (unsigned short)(u >> 16);
}
DEVI float silu(float x) { return x / (1.f + __expf(-x)); }

// ---------------------------------------------------------------- prep kernels
// data f32 [2048][2048] -> xb bf16 [2048][KA]; cols 2048..KA zeroed (xla fills dense later)
__global__ __launch_bounds__(256) void cast_x_kernel(const float* __restrict__ data,
                                                     unsigned short* __restrict__ xb) {
  const int row = blockIdx.x, tid = threadIdx.x;
  const float* src = data + (size_t)row * D;
  unsigned short* dst = xb + (size_t)row * KA;
  const int c = tid * 8;
  float4 v0 = *(const float4*)(src + c);
  float4 v1 = *(const float4*)(src + c + 4);
  ushort4 o0, o1;
  o0.x = f2bf(v0.x); o0.y = f2bf(v0.y); o0.z = f2bf(v0.z); o0.w = f2bf(v0.w);
  o1.x = f2bf(v1.x); o1.y = f2bf(v1.y); o1.z = f2bf(v1.z); o1.w = f2bf(v1.w);
  *(ushort4*)(dst + c) = o0;
  *(ushort4*)(dst + c + 4) = o1;
  if (tid < 16) {
    ushort4 z; z.x = 0; z.y = 0; z.z = 0; z.w = 0;
    *(ushort4*)(dst + D + tid * 4) = z;
  }
}

// dense tokens: xla = x @ la^T ; write 2*xla into xb aug cols.
// One block per token, 4 waves; wave owns 8 r-values (8 acc -> load pipelining works,
// unlike the 32-acc register-starved version that serialized every L2 load).
__global__ __launch_bounds__(256) void xla_kernel(const float* __restrict__ data,
                                                  const float* __restrict__ la1,
                                                  const float* __restrict__ la3,
                                                  unsigned short* __restrict__ xb) {
  const int t = blockIdx.x;                        // dense token 0..1023
  const int wave = threadIdx.x >> 6;               // 0..3
  const int lane = threadIdx.x & 63;
  const float* xr = data + (size_t)(NMOE + t) * D;
  const float* la = ((wave >> 1) == 0) ? la1 : la3;
  const int r0 = (wave & 1) * 8;
  float acc[8];
  #pragma unroll
  for (int r = 0; r < 8; ++r) acc[r] = 0.f;
  #pragma unroll 2
  for (int k = lane; k < D; k += 64) {
    float xv = xr[k];
    #pragma unroll
    for (int r = 0; r < 8; ++r)
      acc[r] = fmaf(xv, la[(size_t)(r0 + r) * D + k], acc[r]);
  }
  #pragma unroll
  for (int r = 0; r < 8; ++r) {
    float v = acc[r];
    #pragma unroll
    for (int s = 32; s > 0; s >>= 1) v += __shfl_xor(v, s);
    acc[r] = v;
  }
  if (lane == 0) {
    unsigned short* dst = xb + (size_t)(NMOE + t) * KA + D + (wave >> 1) * 16 + (wave & 1) * 8;
    #pragma unroll
    for (int r = 0; r < 8; ++r) dst[r] = f2bf(KSCALE * acc[r]);
  }
}

// W1|W3 rows of Btilde: copy row + lb slot in aug cols
__global__ __launch_bounds__(256) void cast_wlb_kernel(const float* __restrict__ W1,
                                                       const float* __restrict__ W3,
                                                       const float* __restrict__ lb1,
                                                       const float* __restrict__ lb3,
                                                       unsigned short* __restrict__ Wt) {
  const int f = blockIdx.x;            // 0..11263
  const int tid = threadIdx.x;
  const bool isW1 = f < DFF;
  const float* src = isW1 ? (W1 + (size_t)f * D) : (W3 + (size_t)(f - DFF) * D);
  unsigned short* dst = Wt + (size_t)f * KA;
  const int c = tid * 8;
  float4 v0 = *(const float4*)(src + c);
  float4 v1 = *(const float4*)(src + c + 4);
  ushort4 o0, o1;
  o0.x = f2bf(v0.x); o0.y = f2bf(v0.y); o0.z = f2bf(v0.z); o0.w = f2bf(v0.w);
  o1.x = f2bf(v1.x); o1.y = f2bf(v1.y); o1.z = f2bf(v1.z); o1.w = f2bf(v1.w);
  *(ushort4*)(dst + c) = o0;
  *(ushort4*)(dst + c + 4) = o1;
  if (tid < 16) {
    unsigned short o[4];
    #pragma unroll
    for (int j = 0; j < 4; ++j) {
      int rel = tid * 4 + j;           // 0..63
      float v = 0.f;
      if (isW1 && rel < 16)                 v = lb1[(size_t)f * 16 + rel];
      if (!isW1 && rel >= 16 && rel < 32)   v = lb3[(size_t)(f - DFF) * 16 + (rel - 16)];
      o[j] = f2bf(v);
    }
    ushort4 ov; ov.x = o[0]; ov.y = o[1]; ov.z = o[2]; ov.w = o[3];
    *(ushort4*)(dst + D + tid * 4) = ov;
  }
}

// A1|A3 rows of Btilde (rows COL_A1..COL_A1+255): copy + zero aug cols
__global__ __launch_bounds__(256) void cast_a13_kernel(const float* __restrict__ A1,
                                                       const float* __restrict__ A3,
                                                       unsigned short* __restrict__ Wt) {
  const int b = blockIdx.x;            // 0..255
  const int tid = threadIdx.x;
  const float* src = (b < 128) ? (A1 + (size_t)b * D) : (A3 + (size_t)(b - 128) * D);
  unsigned short* dst = Wt + (size_t)(COL_A1 + b) * KA;
  const int c = tid * 8;
  float4 v0 = *(const float4*)(src + c);
  float4 v1 = *(const float4*)(src + c + 4);
  ushort4 o0, o1;
  o0.x = f2bf(v0.x); o0.y = f2bf(v0.y); o0.z = f2bf(v0.z); o0.w = f2bf(v0.w);
  o1.x = f2bf(v1.x); o1.y = f2bf(v1.y); o1.z = f2bf(v1.z); o1.w = f2bf(v1.w);
  *(ushort4*)(dst + c) = o0;
  *(ushort4*)(dst + c + 4) = o1;
  if (tid < 16) {
    ushort4 z; z.x = 0; z.y = 0; z.z = 0; z.w = 0;
    *(ushort4*)(dst + D + tid * 4) = z;
  }
}

// W2hat rows: [W2 row | B2_0..7 slots | lb2 slot | 0]
__global__ __launch_bounds__(256) void cast_w2_kernel(const float* __restrict__ W2,
                                                      const float* __restrict__ B2,
                                                      const float* __restrict__ lb2,
                                                      unsigned short* __restrict__ W2t) {
  const int d = blockIdx.x, tid = threadIdx.x;
  const float* src = W2 + (size_t)d * DFF;
  unsigned short* dst = W2t + (size_t)d * KH;
  for (int c = tid * 4; c < DFF; c += 1024) {
    float4 v = *(const float4*)(src + c);
    ushort4 o;
    o.x = f2bf(v.x); o.y = f2bf(v.y); o.z = f2bf(v.z); o.w = f2bf(v.w);
    *(ushort4*)(dst + c) = o;
  }
  if (tid < 48) {
    unsigned short o[4];
    #pragma unroll
    for (int j = 0; j < 4; ++j) {
      int rel = tid * 4 + j;           // 0..191
      float v = 0.f;
      if (rel < 128)      v = B2[(size_t)(rel >> 4) * D * 16 + (size_t)d * 16 + (rel & 15)];
      else if (rel < 144) v = lb2[(size_t)d * 16 + (rel - 128)];
      o[j] = f2bf(v);
    }
    ushort4 ov; ov.x = o[0]; ov.y = o[1]; ov.z = o[2]; ov.w = o[3];
    *(ushort4*)(dst + DFF + tid * 4) = ov;
  }
}

// B1,B3 flat f32->bf16 (each 8*5632*16 = 704*1024 elems)
__global__ __launch_bounds__(256) void cast_flat2_kernel(const float* __restrict__ B1,
                                                         const float* __restrict__ B3,
                                                         unsigned short* __restrict__ B1b,
                                                         unsigned short* __restrict__ B3b) {
  int b = blockIdx.x;                  // 0..1407
  const float* src; unsigned short* dst;
  if (b < 704) { src = B1; dst = B1b; } else { src = B3; dst = B3b; b -= 704; }
  size_t idx = ((size_t)b * 256 + threadIdx.x) * 4;
  float4 v = *(const float4*)(src + idx);
  ushort4 o;
  o.x = f2bf(v.x); o.y = f2bf(v.y); o.z = f2bf(v.z); o.w = f2bf(v.w);
  *(ushort4*)(dst + idx) = o;
}

// A2 (E,R,DFF) -> A2t (E,DFF,R) bf16 ; la2 (R,DFF) -> la2t (DFF,R) bf16
__global__ __launch_bounds__(256) void transpose_ra_kernel(const float* __restrict__ A2,
                                                           const float* __restrict__ la2,
                                                           unsigned short* __restrict__ A2tb,
                                                           unsigned short* __restrict__ la2tb) {
  int f = blockIdx.x * 256 + threadIdx.x;          // 0..5631 (grid.x=22 exact)
  int e = blockIdx.y;                              // 0..7 = A2 expert, 8 = la2
  const float* src = (e < 8) ? (A2 + (size_t)e * 16 * DFF) : la2;
  unsigned short* dst = (e < 8) ? (A2tb + (size_t)e * DFF * 16) : la2tb;
  unsigned short tmp[16];
  #pragma unroll
  for (int r = 0; r < 16; ++r) tmp[r] = f2bf(src[(size_t)r * DFF + f]);
  #pragma unroll
  for (int r = 0; r < 16; ++r) dst[(size_t)f * 16 + r] = tmp[r];
}

// ---------------------------------------------------------------- gating (exact f32)
__global__ __launch_bounds__(256) void gate_kernel(const float* __restrict__ x,
                                                   const float* __restrict__ gW,
                                                   float* __restrict__ logits_out,
                                                   int* __restrict__ gidx,
                                                   float* __restrict__ gwt) {
  int t = blockIdx.x * 4 + (threadIdx.x >> 6);     // one wave per token, 1024 tokens
  int lane = threadIdx.x & 63;
  const float* xr = x + (size_t)t * D;
  float acc[8];
  #pragma unroll
  for (int e = 0; e < 8; ++e) acc[e] = 0.f;
  for (int k = lane; k < D; k += 64) {
    float xv = xr[k];
    #pragma unroll
    for (int e = 0; e < 8; ++e) acc[e] = fmaf(xv, gW[e * D + k], acc[e]);
  }
  #pragma unroll
  for (int e = 0; e < 8; ++e) {
    float v = acc[e];
    #pragma unroll
    for (int s = 32; s > 0; s >>= 1) v += __shfl_xor(v, s);
    acc[e] = v;
  }
  if (lane == 0) {
    #pragma unroll
    for (int e = 0; e < 8; ++e) logits_out[(size_t)t * 8 + e] = acc[e];
    int i1 = 0;
    #pragma unroll
    for (int e = 1; e < 8; ++e) if (acc[e] > acc[i1]) i1 = e;   // ties -> lowest index (jax)
    int i2 = (i1 == 0) ? 1 : 0;
    #pragma unroll
    for (int e = 0; e < 8; ++e) if (e != i1 && acc[e] > acc[i2]) i2 = e;
    float w1 = 1.f / (1.f + expf(acc[i2] - acc[i1]));           // p1/(p1+p2), stable
    gidx[t * 2] = i1; gidx[t * 2 + 1] = i2;
    gwt[t * 2] = w1;  gwt[t * 2 + 1] = 1.f - w1;
  }
}

// ---------------------------------------------------------------- minimal-barrier bf16 GEMM
// C = A(M,K) * B(N,K)^T.  BK=64, per-wave 64x64 output, double-buffered LDS,
// per K-tile: {stage all 8 loads of tile t+1 -> counted vmcnt(8) -> barrier ->
// [16 ds_read + 32 MFMA, compiler-scheduled, NO pinning] -> barrier}.
// XOR-swizzled LDS (granule^row&7, inverse applied on global source) -> 0 conflicts.
// by-FASTEST traversal: consecutive blocks share the B-panel (L2-resident).
// EPI: 1 -> bf16 store; 3 -> f32 plain store.
typedef const void __attribute__((address_space(1)))* gp1_t;
typedef void __attribute__((address_space(3)))* lp3_t;
DEVI void gload_lds16(const void* g, void* l) {
  __builtin_amdgcn_global_load_lds((gp1_t)g, (lp3_t)l, 16, 0, 0);
}
#define S_BARRIER() asm volatile("s_barrier" ::: "memory")

template <int N> DEVI void vmcnt_() {
  static_assert(N == 0 || N == 8, "enumerate literals");
  if constexpr (N == 0) asm volatile("s_waitcnt vmcnt(0)" ::: "memory");
  if constexpr (N == 8) asm volatile("s_waitcnt vmcnt(8)" ::: "memory");
}

template <int BM, int BN, int WM, int WN, int MINW, int EPI>
__global__ __launch_bounds__(WM * WN * 64, MINW) void gemmM(
    const unsigned short* __restrict__ A,
    const unsigned short* __restrict__ B,
    int K,
    float* __restrict__ Cf,
    unsigned short* __restrict__ Cb,
    int ldc, int nby) {
  constexpr int THREADS = WM * WN * 64;
  constexpr int RW = BM / WM;              // 64
  constexpr int CW = BN / WN;              // 64
  static_assert(RW == 64 && CW == 64, "template assumes 64x64 per-wave tile");
  constexpr int ATILE = BM * 128;          // bytes (BM x 64 bf16)
  constexpr int BTILE = BN * 128;
  constexpr int SLOT = ATILE + BTILE;
  constexpr int APARTS = BM * 8 / THREADS;
  constexpr int BPARTS = BN * 8 / THREADS;
  static_assert(APARTS + BPARTS == 8, "vmcnt gate literal assumes 8 loads/tile");

  __shared__ __align__(16) char smem[2 * SLOT];

  const int tid = threadIdx.x;
  const int wave = tid >> 6, lane = tid & 63;
  const int wm = wave / WN, wn = wave % WN;
  const int r15 = lane & 15, g = lane >> 4;

  // XCD-aware bijective block swizzle (nwg % 8 == 0 for all our launches)
  const int nwg = (int)gridDim.x;
  const int bid = (int)blockIdx.x;
  const int wgid = (bid & 7) * (nwg >> 3) + (bid >> 3);
  // by-fastest: consecutive wgids share bx (B-panel stays L2-resident)
  const int by = wgid % nby, bx = wgid / nby;

  const unsigned short* Ablk = A + (size_t)by * BM * K;
  const unsigned short* Bblk = B + (size_t)bx * BN * K;

  int sgoA[APARTS], sgoB[BPARTS];
  #pragma unroll
  for (int j = 0; j < APARTS; ++j) {
    int tt = j * THREADS + tid;
    int row = tt >> 3;
    sgoA[j] = row * K + (((tt & 7) ^ (row & 7)) << 3);
  }
  #pragma unroll
  for (int j = 0; j < BPARTS; ++j) {
    int tt = j * THREADS + tid;
    int row = tt >> 3;
    sgoB[j] = row * K + (((tt & 7) ^ (row & 7)) << 3);
  }
  auto stage = [&](int p, int k0) {
    char* s = smem + p * SLOT;
    #pragma unroll
    for (int j = 0; j < APARTS; ++j)
      gload_lds16((const char*)Ablk + ((size_t)(sgoA[j] + k0) << 1),
                  s + j * (THREADS * 16) + wave * 1024);
    #pragma unroll
    for (int j = 0; j < BPARTS; ++j)
      gload_lds16((const char*)Bblk + ((size_t)(sgoB[j] + k0) << 1),
                  s + ATILE + j * (THREADS * 16) + wave * 1024);
  };

  const int arow0 = (wm * RW + r15) * 128;
  const int brow0 = (wn * CW + r15) * 128;
  const int s0 = ((g ^ (r15 & 7)) << 4);
  const int s1 = (((4 + g) ^ (r15 & 7)) << 4);

  f32x4 acc[4][4];
  #pragma unroll
  for (int m = 0; m < 4; ++m)
    #pragma unroll
    for (int n = 0; n < 4; ++n)
      #pragma unroll
      for (int j = 0; j < 4; ++j) acc[m][n][j] = 0.f;

  const int NT = K >> 6;

  stage(0, 0);

  for (int t = 0; t < NT; ++t) {
    const int p = t & 1;
    if (t + 1 < NT) {
      stage(p ^ 1, (t + 1) << 6);
      vmcnt_<8>();
    } else {
      vmcnt_<0>();
    }
    S_BARRIER();

    const char* sA = smem + p * SLOT;
    const char* sB = sA + ATILE;

    short8 bq[4][2], av[4][2];
    #pragma unroll
    for (int n = 0; n < 4; ++n) {
      bq[n][0] = *(const short8*)(sB + brow0 + n * 2048 + s0);
      bq[n][1] = *(const short8*)(sB + brow0 + n * 2048 + s1);
    }
    #pragma unroll
    for (int m = 0; m < 4; ++m) {
      av[m][0] = *(const short8*)(sA + arow0 + m * 2048 + s0);
      av[m][1] = *(const short8*)(sA + arow0 + m * 2048 + s1);
    }
    #pragma unroll
    for (int m = 0; m < 4; ++m)
      #pragma unroll
      for (int n = 0; n < 4; ++n)
        #pragma unroll
        for (int kk = 0; kk < 2; ++kk)
          acc[m][n] = __builtin_amdgcn_mfma_f32_16x16x32_bf16(
              av[m][kk], bq[n][kk], acc[m][n], 0, 0, 0);

    S_BARRIER();
  }

  // epilogue: C/D layout col=lane&15, row=(lane>>4)*4+reg  [m89-verified]
  const int row0 = by * BM + wm * RW + (g << 2);
  const int col0 = bx * BN + wn * CW + r15;
  #pragma unroll
  for (int m = 0; m < 4; ++m) {
    #pragma unroll
    for (int n = 0; n < 4; ++n) {
      int col = col0 + n * 16;
      #pragma unroll
      for (int j = 0; j < 4; ++j) {
        int row = row0 + m * 16 + j;
        size_t off = (size_t)row * ldc + col;
        float v = acc[m][n][j];
        if (EPI == 1) Cb[off] = f2bf(v);
        else          Cf[off] = v;
      }
    }
  }
}

// ---------------------------------------------------------------- h / combine / q kernel
DEVI float dot16bf(const float* a, const unsigned short* w) {
  short8 w0 = *(const short8*)w;
  short8 w1 = *(const short8*)(w + 8);
  float s0 = 0.f, s1 = 0.f;
  #pragma unroll
  for (int i = 0; i < 8; ++i) {
    s0 = fmaf(a[i],     bf2f((unsigned short)w0[i]), s0);
    s1 = fmaf(a[8 + i], bf2f((unsigned short)w1[i]), s1);
  }
  return s0 + s1;
}

__global__ __launch_bounds__(256) void h_kernel(
    const unsigned short* __restrict__ GU,      // [NTOK][NW] bf16
    const unsigned short* __restrict__ B1b,     // [8][DFF][16]
    const unsigned short* __restrict__ B3b,
    const unsigned short* __restrict__ A2tb,    // [8][DFF][16]
    const unsigned short* __restrict__ la2tb,   // [DFF][16]
    const int* __restrict__ gidx, const float* __restrict__ gwt,
    unsigned short* __restrict__ Hb) {          // [NTOK][KH]
  const int t = blockIdx.x;
  const int tid = threadIdx.x;
  const unsigned short* gu = GU + (size_t)t * NW;
  unsigned short* hrow = Hb + (size_t)t * KH;
  float qacc[32];
  #pragma unroll
  for (int r = 0; r < 32; ++r) qacc[r] = 0.f;
  int e1 = 0, e2 = 1;
  float w1 = 0.f, w2 = 0.f;

  if (t < NMOE) {
    e1 = gidx[t * 2]; e2 = gidx[t * 2 + 1];
    w1 = gwt[t * 2]; w2 = gwt[t * 2 + 1];
    float xa1a[16], xa1b[16], xa3a[16], xa3b[16];
    #pragma unroll
    for (int r = 0; r < 16; ++r) {
      xa1a[r] = bf2f(gu[COL_A1 + e1 * 16 + r]);
      xa1b[r] = bf2f(gu[COL_A1 + e2 * 16 + r]);
      xa3a[r] = bf2f(gu[COL_A3 + e1 * 16 + r]);
      xa3b[r] = bf2f(gu[COL_A3 + e2 * 16 + r]);
    }
    const unsigned short* B1e1 = B1b + (size_t)e1 * DFF * 16;
    const unsigned short* B1e2 = B1b + (size_t)e2 * DFF * 16;
    const unsigned short* B3e1 = B3b + (size_t)e1 * DFF * 16;
    const unsigned short* B3e2 = B3b + (size_t)e2 * DFF * 16;
    const unsigned short* A2e1 = A2tb + (size_t)e1 * DFF * 16;
    const unsigned short* A2e2 = A2tb + (size_t)e2 * DFF * 16;
    for (int i = 0; i < 22; ++i) {
      int f = tid + i * 256;
      float bg = bf2f(gu[f]), bu = bf2f(gu[DFF + f]);
      float dg1 = dot16bf(xa1a, B1e1 + f * 16);
      float du1 = dot16bf(xa3a, B3e1 + f * 16);
      float dg2 = dot16bf(xa1b, B1e2 + f * 16);
      float du2 = dot16bf(xa3b, B3e2 + f * 16);
      float h1 = silu(bg + KSCALE * dg1) * (bu + KSCALE * du1);
      float h2 = silu(bg + KSCALE * dg2) * (bu + KSCALE * du2);
      hrow[f] = f2bf(w1 * h1 + w2 * h2);
      short8 a0 = *(const short8*)(A2e1 + f * 16);
      short8 a1 = *(const short8*)(A2e1 + f * 16 + 8);
      short8 b0 = *(const short8*)(A2e2 + f * 16);
      short8 b1 = *(const short8*)(A2e2 + f * 16 + 8);
      #pragma unroll
      for (int r = 0; r < 8; ++r) {
        qacc[r]      = fmaf(h1, bf2f((unsigned short)a0[r]), qacc[r]);
        qacc[8 + r]  = fmaf(h1, bf2f((unsigned short)a1[r]), qacc[8 + r]);
        qacc[16 + r] = fmaf(h2, bf2f((unsigned short)b0[r]), qacc[16 + r]);
        qacc[24 + r] = fmaf(h2, bf2f((unsigned short)b1[r]), qacc[24 + r]);
      }
    }
  } else {
    // dense: LoRA folded into GU; only h and q = h @ la2^T remain
    for (int i = 0; i < 22; ++i) {
      int f = tid + i * 256;
      float bg = bf2f(gu[f]), bu = bf2f(gu[DFF + f]);
      float h = silu(bg) * bu;
      hrow[f] = f2bf(h);
      short8 a0 = *(const short8*)(la2tb + f * 16);
      short8 a1 = *(const short8*)(la2tb + f * 16 + 8);
      #pragma unroll
      for (int r = 0; r < 8; ++r) {
        qacc[r]     = fmaf(h, bf2f((unsigned short)a0[r]), qacc[r]);
        qacc[8 + r] = fmaf(h, bf2f((unsigned short)a1[r]), qacc[8 + r]);
      }
    }
  }

  // reduce 32 partials across 256 threads
  #pragma unroll
  for (int r = 0; r < 32; ++r) {
    float v = qacc[r];
    #pragma unroll
    for (int s = 32; s > 0; s >>= 1) v += __shfl_xor(v, s);
    qacc[r] = v;
  }
  __shared__ float red[4][32];
  const int wave = tid >> 6, lane = tid & 63;
  if (lane == 0) {
    #pragma unroll
    for (int r = 0; r < 32; ++r) red[wave][r] = qacc[r];
  }
  __syncthreads();
  // write augmented-K tail: cols DFF..DFF+191 (expert q slots, dense slot, pad)
  if (tid < 192) {
    int e = tid >> 4, r = tid & 15;
    float v = 0.f;
    if (t < NMOE) {
      if (e == e1)      v = KSCALE * w1 * (red[0][r] + red[1][r] + red[2][r] + red[3][r]);
      else if (e == e2) v = KSCALE * w2 * (red[0][16 + r] + red[1][16 + r] + red[2][16 + r] + red[3][16 + r]);
    } else {
      if (e == 8)       v = KSCALE * (red[0][r] + red[1][r] + red[2][r] + red[3][r]);
    }
    hrow[DFF + tid] = f2bf(v);
  }
}

// ---------------------------------------------------------------- host
extern "C" void kernel_launch(void* const* d_in, const int* in_sizes, int n_in,
                              void* d_out, int out_size, void* d_ws, size_t ws_size,
                              hipStream_t stream) {
  (void)in_sizes; (void)n_in; (void)out_size; (void)ws_size;
  const float* data = (const float*)d_in[0];
  const float* W1   = (const float*)d_in[1];
  const float* W3   = (const float*)d_in[2];
  const float* W2   = (const float*)d_in[3];
  const float* gW   = (const float*)d_in[4];
  const float* A1   = (const float*)d_in[5];
  const float* B1   = (const float*)d_in[6];
  const float* A3   = (const float*)d_in[7];
  const float* B3   = (const float*)d_in[8];
  const float* A2   = (const float*)d_in[9];
  const float* B2   = (const float*)d_in[10];
  const float* la1  = (const float*)d_in[11];
  const float* lb1  = (const float*)d_in[12];
  const float* la3  = (const float*)d_in[13];
  const float* lb3  = (const float*)d_in[14];
  const float* la2  = (const float*)d_in[15];
  const float* lb2  = (const float*)d_in[16];

  char* w = (char*)d_ws;
  size_t off = 0;
  auto alloc = [&](size_t bytes) -> char* {
    char* p = w + off;
    off += (bytes + 255) & ~(size_t)255;
    return p;
  };
  unsigned short* xb    = (unsigned short*)alloc((size_t)NTOK * KA * 2);      // 8.65 MB
  unsigned short* W13t  = (unsigned short*)alloc((size_t)NW * KA * 2);        // 49.2 MB
  unsigned short* W2t   = (unsigned short*)alloc((size_t)D * KH * 2);         // 23.9 MB
  unsigned short* B1b   = (unsigned short*)alloc((size_t)8 * DFF * 16 * 2);
  unsigned short* B3b   = (unsigned short*)alloc((size_t)8 * DFF * 16 * 2);
  unsigned short* A2tb  = (unsigned short*)alloc((size_t)8 * DFF * 16 * 2);
  unsigned short* la2tb = (unsigned short*)alloc((size_t)DFF * 16 * 2);
  int*   gidx = (int*)alloc((size_t)NMOE * 2 * 4);
  float* gwt  = (float*)alloc((size_t)NMOE * 2 * 4);
  unsigned short* GU    = (unsigned short*)alloc((size_t)NTOK * NW * 2);      // 47.7 MB

  // Aliased scratch: Hb (23.9 MB) into W13t region (dead after up-GEMM)
  unsigned short* Hb = W13t;

  // ---- prep
  cast_x_kernel<<<NTOK, 256, 0, stream>>>(data, xb);
  cast_wlb_kernel<<<2 * DFF, 256, 0, stream>>>(W1, W3, lb1, lb3, W13t);
  cast_a13_kernel<<<256, 256, 0, stream>>>(A1, A3, W13t);
  hipMemsetAsync(W13t + (size_t)(COL_A3 + 128) * KA, 0,
                 (size_t)(NW - (COL_A3 + 128)) * KA * 2, stream);  // pad rows -> 0
  cast_w2_kernel<<<D, 256, 0, stream>>>(W2, B2, lb2, W2t);
  cast_flat2_kernel<<<1408, 256, 0, stream>>>(B1, B3, B1b, B3b);
  transpose_ra_kernel<<<dim3(DFF / 256, 9), 256, 0, stream>>>(A2, la2, A2tb, la2tb);

  // ---- gating (writes logits f32) + dense xla into xb aug cols
  gate_kernel<<<NMOE / 4, 256, 0, stream>>>(data, gW,
      (float*)d_out + (size_t)NTOK * D, gidx, gwt);
  xla_kernel<<<NMOE, 256, 0, stream>>>(data, la1, la3, xb);

  // ---- up-GEMM: 2048 x 11648 x 2112 (augmented K folds dense LoRA), bf16 -> GU
  gemmM<128, 128, 2, 2, 2, 1><<<(NTOK / 128) * (NW / 128), 256, 0, stream>>>(
      xb, W13t, KA, (float*)nullptr, GU, NW, NTOK / 128);

  // ---- h / per-expert q -> Hb augmented rows [h | q slots]
  h_kernel<<<NTOK, 256, 0, stream>>>(GU, B1b, B3b, A2tb, la2tb, gidx, gwt, Hb);

  // ---- down-GEMM: 2048 x 2048 x 5824 (augmented K folds ALL down-LoRA), f32 -> d_out
  gemmM<128, 128, 2, 2, 2, 3><<<(NTOK / 128) * (D / 128), 256, 0, stream>>>(
      Hb, W2t, KH, (float*)d_out, (unsigned short*)nullptr, D, NTOK / 128);
}